// Round 2
// baseline (369.519 us; speedup 1.0000x reference)
//
#include <hip/hip_runtime.h>
#include <stdint.h>

typedef unsigned short u16;
typedef __attribute__((ext_vector_type(8))) short short8;
typedef __attribute__((ext_vector_type(4))) float f32x4;

#define M_DIM 8192
#define N_DIM 4096
#define K_DIM 4096

// ---------- fp32 -> bf16 (RNE), 8 elems/thread ----------
__device__ inline u16 f32_to_bf16_rne(float f) {
    uint32_t b = __builtin_bit_cast(uint32_t, f);
    b += 0x7fffu + ((b >> 16) & 1u);
    return (u16)(b >> 16);
}

__global__ __launch_bounds__(256)
void cvt_f32_to_bf16_k(const float* __restrict__ in, u16* __restrict__ out, int n_vec8) {
    int stride = gridDim.x * blockDim.x;
    for (int i = blockIdx.x * blockDim.x + threadIdx.x; i < n_vec8; i += stride) {
        const float4* p = reinterpret_cast<const float4*>(in) + 2 * (size_t)i;
        float4 a = p[0];
        float4 b = p[1];
        float v[8] = {a.x, a.y, a.z, a.w, b.x, b.y, b.z, b.w};
        short8 r;
#pragma unroll
        for (int j = 0; j < 8; ++j) r[j] = (short)f32_to_bf16_rne(v[j]);
        *reinterpret_cast<short8*>(out + 8 * (size_t)i) = r;
    }
}

// ---------- 256x256 8-phase bf16 GEMM (m201 structure) ----------
// A: [M][K] bf16, B: [N][K] bf16 (B^T layout), C: [M][N] f32
// 512 threads = 8 waves (2 M x 4 N); per-wave output 128x64; BK=64.
// LDS: [dbuf][mat(A/B)][half][128*64] bf16 = 128 KiB, st_16x32 XOR swizzle.

__device__ __forceinline__ uint32_t swz(uint32_t lin) {
    return lin ^ (((lin >> 9) & 1u) << 5);
}

#define BAR() do { asm volatile("" ::: "memory"); __builtin_amdgcn_s_barrier(); asm volatile("" ::: "memory"); } while (0)
#define WAIT_LGKM0() asm volatile("s_waitcnt lgkmcnt(0)" ::: "memory")
#define WAIT_VM4() asm volatile("s_waitcnt vmcnt(4)" ::: "memory")
#define WAIT_VM0() asm volatile("s_waitcnt vmcnt(0)" ::: "memory")

// MFMA quadrant: 4 m-frags x 2 n-frags x 2 k-slices = 16 MFMA (all indices fold)
#define QUAD(MH, NH, BB)                                                          \
    _Pragma("unroll")                                                             \
    for (int ks = 0; ks < 2; ++ks) {                                              \
        _Pragma("unroll")                                                         \
        for (int m = 0; m < 4; ++m) {                                             \
            _Pragma("unroll")                                                     \
            for (int n = 0; n < 2; ++n) {                                         \
                acc[(MH) * 4 + m][(NH) * 2 + n] =                                 \
                    __builtin_amdgcn_mfma_f32_16x16x32_bf16(                      \
                        a[ks][m], BB[ks][n], acc[(MH) * 4 + m][(NH) * 2 + n],     \
                        0, 0, 0);                                                 \
            }                                                                     \
        }                                                                         \
    }

#define READ_A(BUF, MH)                                                           \
    _Pragma("unroll")                                                             \
    for (int ks = 0; ks < 2; ++ks) {                                              \
        _Pragma("unroll")                                                         \
        for (int m = 0; m < 4; ++m) {                                             \
            a[ks][m] = FRAG(As[BUF], ((MH) * 4 + m) * 2048u + ks * 64u + aoff);   \
        }                                                                         \
    }

#define READ_B(BUF, NH, BB)                                                       \
    _Pragma("unroll")                                                             \
    for (int ks = 0; ks < 2; ++ks) {                                              \
        _Pragma("unroll")                                                         \
        for (int n = 0; n < 2; ++n) {                                             \
            BB[ks][n] = FRAG(Bs[BUF], ((NH) * 2 + n) * 2048u + ks * 64u + boff);  \
        }                                                                         \
    }

__global__ __launch_bounds__(512, 2)
void gemm_8phase(const u16* __restrict__ A, const u16* __restrict__ B,
                 const float* __restrict__ bias, float* __restrict__ C) {
    __shared__ __align__(16) u16 lds[2][2][2][128 * 64];   // 128 KiB

    const int tid  = threadIdx.x;
    const int wave = tid >> 6;
    const int lane = tid & 63;

    // T1: XCD-aware bijective swizzle (nwg=512, 512%8==0)
    const uint32_t wg = (blockIdx.x & 7u) * 64u + (blockIdx.x >> 3);
    const int bx = (int)(wg % (N_DIM / 256));
    const int by = (int)(wg / (N_DIM / 256));
    const int brow = by * 256;
    const int bcol = bx * 256;

    const int wr = wave >> 2;   // 0..1 -> 128 output rows each
    const int wc = wave & 3;    // 0..3 -> 64 output cols each

    // staging source geometry: half-tile = 128 rows x 64 cols bf16 = 1024 chunks x 16B.
    // physical chunk cp written linearly by global_load_lds; logical chunk
    // cl = cp ^ ((cp>>5 & 1) << 1)  (byte-level st_16x32: lin ^= ((lin>>9)&1)<<5)
    const uint32_t cp0 = (uint32_t)(wave * 64 + lane);
    const uint32_t cp1 = cp0 + 512u;
    const uint32_t cl0 = cp0 ^ (((cp0 >> 5) & 1u) << 1);
    const uint32_t cl1 = cp1 ^ (((cp1 >> 5) & 1u) << 1);
    const uint32_t sr0 = cl0 >> 3, sc0 = (cl0 & 7u) * 8u;
    const uint32_t sr1 = cl1 >> 3, sc1 = (cl1 & 7u) * 8u;

    const u16* pA[2] = { A + (size_t)(brow)       * K_DIM,
                         A + (size_t)(brow + 128) * K_DIM };
    const u16* pB[2] = { B + (size_t)(bcol)       * K_DIM,
                         B + (size_t)(bcol + 128) * K_DIM };

    // frag-read lane byte offsets within a [128][64] half (row*128B + k-part)
    const uint32_t kb   = (uint32_t)(lane >> 4) * 16u;
    const uint32_t aoff = (uint32_t)(lane & 15) * 128u + kb;
    const uint32_t boff = (uint32_t)(wc & 1) * 8192u + (uint32_t)(lane & 15) * 128u + kb;

    const u16* As[2] = { &lds[0][0][wr][0],      &lds[1][0][wr][0] };
    const u16* Bs[2] = { &lds[0][1][wc >> 1][0], &lds[1][1][wc >> 1][0] };

    auto STAGE = [&](const u16* gbase, u16* lhalf, int k0) {
        __builtin_amdgcn_global_load_lds(
            (const __attribute__((address_space(1))) uint32_t*)(gbase + (size_t)sr0 * K_DIM + k0 + sc0),
            (__attribute__((address_space(3))) uint32_t*)(lhalf + wave * 512), 16, 0, 0);
        __builtin_amdgcn_global_load_lds(
            (const __attribute__((address_space(1))) uint32_t*)(gbase + (size_t)sr1 * K_DIM + k0 + sc1),
            (__attribute__((address_space(3))) uint32_t*)(lhalf + 4096 + wave * 512), 16, 0, 0);
    };

    auto FRAG = [&](const u16* lhalf, uint32_t lin) -> short8 {
        return *reinterpret_cast<const short8*>(
            reinterpret_cast<const char*>(lhalf) + swz(lin));
    };

    f32x4 acc[8][4];
#pragma unroll
    for (int m = 0; m < 8; ++m)
#pragma unroll
        for (int n = 0; n < 4; ++n) acc[m][n] = (f32x4){0.f, 0.f, 0.f, 0.f};

    short8 a[2][4], b0[2][2], b1[2][2];

    // ---- prologue: tile0 fully + tile1 B-halves; wait tile0 landed ----
    STAGE(pA[0], &lds[0][0][0][0], 0);
    STAGE(pA[1], &lds[0][0][1][0], 0);
    STAGE(pB[0], &lds[0][1][0][0], 0);
    STAGE(pB[1], &lds[0][1][1][0], 0);
    STAGE(pB[0], &lds[1][1][0][0], 64);
    STAGE(pB[1], &lds[1][1][1][0], 64);
    WAIT_VM4();
    BAR();

    // ---- main loop: iter i computes tiles a=2i (buf0), b=2i+1 (buf1) ----
    // stage schedule: P1 b.Ah0 | P2 b.Ah1 | P3 (a+2).Bh0 | P4 (a+2).Bh1 |
    //                 P5 (a+2).Ah0 | P6 (a+2).Ah1 | P7 (b+2).Bh0 | P8 (b+2).Bh1
    // vmcnt(4) at P4 (tile b landed) and P8 (tile a+2 landed).
    for (int i = 0; i < K_DIM / 128; ++i) {
        const int k_b  = (2 * i + 1) * 64;                    // <= 4032, no wrap
        const int k_a2 = ((2 * i + 2) * 64) & (K_DIM - 1);    // wraps harmlessly on last iter
        const int k_b2 = ((2 * i + 3) * 64) & (K_DIM - 1);

        // P1: tile a, Q(mh0,nh0)
        READ_A(0, 0);
        READ_B(0, 0, b0);
        STAGE(pA[0], &lds[1][0][0][0], k_b);
        BAR(); WAIT_LGKM0();
        __builtin_amdgcn_s_setprio(1);
        QUAD(0, 0, b0);
        __builtin_amdgcn_s_setprio(0);
        BAR();

        // P2: Q(mh0,nh1)
        READ_B(0, 1, b1);
        STAGE(pA[1], &lds[1][0][1][0], k_b);
        BAR(); WAIT_LGKM0();
        __builtin_amdgcn_s_setprio(1);
        QUAD(0, 1, b1);
        __builtin_amdgcn_s_setprio(0);
        BAR();

        // P3: Q(mh1,nh0)
        READ_A(0, 1);
        STAGE(pB[0], &lds[0][1][0][0], k_a2);
        BAR(); WAIT_LGKM0();
        __builtin_amdgcn_s_setprio(1);
        QUAD(1, 0, b0);
        __builtin_amdgcn_s_setprio(0);
        BAR();

        // P4: Q(mh1,nh1) + counted vmcnt for tile b
        STAGE(pB[1], &lds[0][1][1][0], k_a2);
        BAR(); WAIT_LGKM0();
        __builtin_amdgcn_s_setprio(1);
        QUAD(1, 1, b1);
        __builtin_amdgcn_s_setprio(0);
        WAIT_VM4();
        BAR();

        // P5: tile b, Q(mh0,nh0)
        READ_A(1, 0);
        READ_B(1, 0, b0);
        STAGE(pA[0], &lds[0][0][0][0], k_a2);
        BAR(); WAIT_LGKM0();
        __builtin_amdgcn_s_setprio(1);
        QUAD(0, 0, b0);
        __builtin_amdgcn_s_setprio(0);
        BAR();

        // P6: Q(mh0,nh1)
        READ_B(1, 1, b1);
        STAGE(pA[1], &lds[0][0][1][0], k_a2);
        BAR(); WAIT_LGKM0();
        __builtin_amdgcn_s_setprio(1);
        QUAD(0, 1, b1);
        __builtin_amdgcn_s_setprio(0);
        BAR();

        // P7: Q(mh1,nh0)
        READ_A(1, 1);
        STAGE(pB[0], &lds[1][1][0][0], k_b2);
        BAR(); WAIT_LGKM0();
        __builtin_amdgcn_s_setprio(1);
        QUAD(1, 0, b0);
        __builtin_amdgcn_s_setprio(0);
        BAR();

        // P8: Q(mh1,nh1) + counted vmcnt for tile a+2
        STAGE(pB[1], &lds[1][1][1][0], k_b2);
        BAR(); WAIT_LGKM0();
        __builtin_amdgcn_s_setprio(1);
        QUAD(1, 1, b1);
        __builtin_amdgcn_s_setprio(0);
        WAIT_VM4();
        BAR();
    }

    WAIT_VM0();   // drain wrapped prefetches before ending

    // ---- epilogue: C/D layout col=lane&15, row=(lane>>4)*4+j ----
    const int orow = brow + wr * 128 + (lane >> 4) * 4;
    const int ocol = bcol + wc * 64 + (lane & 15);
#pragma unroll
    for (int n = 0; n < 4; ++n) {
        const int c = ocol + n * 16;
        const float bv = bias[c];
#pragma unroll
        for (int m = 0; m < 8; ++m) {
#pragma unroll
            for (int j = 0; j < 4; ++j) {
                C[(size_t)(orow + m * 16 + j) * N_DIM + c] = acc[m][n][j] + bv;
            }
        }
    }
}

// ---------- fallback (ws too small): correct, slow fp32 ----------
__global__ __launch_bounds__(256)
void gemm_f32_naive(const float* __restrict__ x, const float* __restrict__ w,
                    const float* __restrict__ bias, float* __restrict__ out) {
    const size_t total = (size_t)M_DIM * N_DIM;
    const size_t stride = (size_t)gridDim.x * blockDim.x;
    for (size_t idx = (size_t)blockIdx.x * blockDim.x + threadIdx.x; idx < total; idx += stride) {
        const int b = (int)(idx / N_DIM);
        const int o = (int)(idx % N_DIM);
        const float* xr = x + (size_t)b * K_DIM;
        const float* wr = w + (size_t)o * K_DIM;
        float s = bias[o];
        for (int k = 0; k < K_DIM; ++k) s = fmaf(xr[k], wr[k], s);
        out[idx] = s;
    }
}

extern "C" void kernel_launch(void* const* d_in, const int* in_sizes, int n_in,
                              void* d_out, int out_size, void* d_ws, size_t ws_size,
                              hipStream_t stream) {
    const float* x    = (const float*)d_in[0];
    const float* w    = (const float*)d_in[1];
    const float* bias = (const float*)d_in[2];
    float* out = (float*)d_out;

    const size_t xb_elems = (size_t)M_DIM * K_DIM;
    const size_t wb_elems = (size_t)N_DIM * K_DIM;
    const size_t need = (xb_elems + wb_elems) * sizeof(u16);

    if (ws_size >= need) {
        u16* xb = (u16*)d_ws;
        u16* wb = xb + xb_elems;
        cvt_f32_to_bf16_k<<<2048, 256, 0, stream>>>(x, xb, (int)(xb_elems / 8));
        cvt_f32_to_bf16_k<<<2048, 256, 0, stream>>>(w, wb, (int)(wb_elems / 8));
        const int nwg = (M_DIM / 256) * (N_DIM / 256);   // 32*16 = 512
        gemm_8phase<<<nwg, 512, 0, stream>>>(xb, wb, bias, out);
    } else {
        gemm_f32_naive<<<4096, 256, 0, stream>>>(x, w, bias, out);
    }
}

// Round 3
// 344.586 us; speedup vs baseline: 1.0724x; 1.0724x over previous
//
#include <hip/hip_runtime.h>
#include <stdint.h>

typedef unsigned short u16;
typedef __attribute__((ext_vector_type(8))) short short8;
typedef __attribute__((ext_vector_type(4))) float f32x4;

#define M_DIM 8192
#define N_DIM 4096
#define K_DIM 4096

// ---------- fp32 -> bf16 (RNE), 8 elems/thread ----------
__device__ inline u16 f32_to_bf16_rne(float f) {
    uint32_t b = __builtin_bit_cast(uint32_t, f);
    b += 0x7fffu + ((b >> 16) & 1u);
    return (u16)(b >> 16);
}

__global__ __launch_bounds__(256)
void cvt_f32_to_bf16_k(const float* __restrict__ in, u16* __restrict__ out, int n_vec8) {
    int stride = gridDim.x * blockDim.x;
    for (int i = blockIdx.x * blockDim.x + threadIdx.x; i < n_vec8; i += stride) {
        const float4* p = reinterpret_cast<const float4*>(in) + 2 * (size_t)i;
        float4 a = p[0];
        float4 b = p[1];
        float v[8] = {a.x, a.y, a.z, a.w, b.x, b.y, b.z, b.w};
        short8 r;
#pragma unroll
        for (int j = 0; j < 8; ++j) r[j] = (short)f32_to_bf16_rne(v[j]);
        *reinterpret_cast<short8*>(out + 8 * (size_t)i) = r;
    }
}

// ---------- 256x256 8-phase bf16 GEMM (m201 structure) ----------
// A: [M][K] bf16, B: [N][K] bf16 (B^T layout), C: [M][N] f32
// 512 threads = 8 waves (2 M x 4 N); per-wave output 128x64; BK=64.
// LDS: [dbuf][mat(A/B)][half][128*64] bf16 = 128 KiB.
// Swizzle: rows are 128 B; S(a) = a ^ (((a>>7)&7)<<4)  (involution, spreads
// 8 consecutive rows across all 32 banks; remaining aliasing is 2-way = free).

__device__ __forceinline__ uint32_t swz(uint32_t a) {
    return a ^ (((a >> 7) & 7u) << 4);
}

#define BAR() do { asm volatile("" ::: "memory"); __builtin_amdgcn_s_barrier(); asm volatile("" ::: "memory"); } while (0)
#define WAIT_LGKM0() asm volatile("s_waitcnt lgkmcnt(0)" ::: "memory")
#define WAIT_VM4() asm volatile("s_waitcnt vmcnt(4)" ::: "memory")
#define WAIT_VM0() asm volatile("s_waitcnt vmcnt(0)" ::: "memory")

// MFMA quadrant: 4 m-frags x 2 n-frags x 2 k-slices = 16 MFMA
#define QUAD(MH, NH, BB)                                                          \
    _Pragma("unroll")                                                             \
    for (int ks = 0; ks < 2; ++ks) {                                              \
        _Pragma("unroll")                                                         \
        for (int m = 0; m < 4; ++m) {                                             \
            _Pragma("unroll")                                                     \
            for (int n = 0; n < 2; ++n) {                                         \
                acc[(MH) * 4 + m][(NH) * 2 + n] =                                 \
                    __builtin_amdgcn_mfma_f32_16x16x32_bf16(                      \
                        a[ks][m], BB[ks][n], acc[(MH) * 4 + m][(NH) * 2 + n],     \
                        0, 0, 0);                                                 \
            }                                                                     \
        }                                                                         \
    }

#define READ_A(BUF, MH)                                                           \
    _Pragma("unroll")                                                             \
    for (int ks = 0; ks < 2; ++ks) {                                              \
        _Pragma("unroll")                                                         \
        for (int m = 0; m < 4; ++m) {                                             \
            a[ks][m] = FRAG(As[BUF], ((MH) * 4 + m) * 2048u + ks * 64u + aoff);   \
        }                                                                         \
    }

#define READ_B(BUF, NH, BB)                                                       \
    _Pragma("unroll")                                                             \
    for (int ks = 0; ks < 2; ++ks) {                                              \
        _Pragma("unroll")                                                         \
        for (int n = 0; n < 2; ++n) {                                             \
            BB[ks][n] = FRAG(Bs[BUF], ((NH) * 2 + n) * 2048u + ks * 64u + boff);  \
        }                                                                         \
    }

__global__ __launch_bounds__(512, 2)
void gemm_8phase(const u16* __restrict__ A, const u16* __restrict__ B,
                 const float* __restrict__ bias, float* __restrict__ C) {
    __shared__ __align__(16) u16 lds[2][2][2][128 * 64];   // 128 KiB

    const int tid  = threadIdx.x;
    const int wave = tid >> 6;
    const int lane = tid & 63;

    // T1: XCD-aware bijective swizzle (nwg=512, 512%8==0)
    const uint32_t wg = (blockIdx.x & 7u) * 64u + (blockIdx.x >> 3);
    const int bx = (int)(wg % (N_DIM / 256));
    const int by = (int)(wg / (N_DIM / 256));
    const int brow = by * 256;
    const int bcol = bx * 256;

    const int wr = wave >> 2;   // 0..1 -> 128 output rows each
    const int wc = wave & 3;    // 0..3 -> 64 output cols each

    // staging: half-tile = 128 rows x 64 cols bf16 = 1024 chunks x 16B.
    // physical chunk cp (linear global_load_lds dest) holds LOGICAL chunk
    // cl = cp ^ ((cp>>3)&7)   (16B-chunk form of S; involution)
    const uint32_t cp0 = (uint32_t)(wave * 64 + lane);
    const uint32_t cp1 = cp0 + 512u;
    const uint32_t cl0 = cp0 ^ ((cp0 >> 3) & 7u);
    const uint32_t cl1 = cp1 ^ ((cp1 >> 3) & 7u);
    const uint32_t sr0 = cl0 >> 3, sc0 = (cl0 & 7u) * 8u;   // row, col(bf16)
    const uint32_t sr1 = cl1 >> 3, sc1 = (cl1 & 7u) * 8u;

    const u16* pA[2] = { A + (size_t)(brow)       * K_DIM,
                         A + (size_t)(brow + 128) * K_DIM };
    const u16* pB[2] = { B + (size_t)(bcol)       * K_DIM,
                         B + (size_t)(bcol + 128) * K_DIM };

    // frag-read lane byte offsets within a [128][64] half (row*128B + k-part)
    const uint32_t kb   = (uint32_t)(lane >> 4) * 16u;
    const uint32_t aoff = (uint32_t)(lane & 15) * 128u + kb;
    const uint32_t boff = (uint32_t)(wc & 1) * 8192u + (uint32_t)(lane & 15) * 128u + kb;

    const u16* As[2] = { &lds[0][0][wr][0],      &lds[1][0][wr][0] };
    const u16* Bs[2] = { &lds[0][1][wc >> 1][0], &lds[1][1][wc >> 1][0] };

    auto STAGE = [&](const u16* gbase, u16* lhalf, int k0) {
        __builtin_amdgcn_global_load_lds(
            (const __attribute__((address_space(1))) uint32_t*)(gbase + (size_t)sr0 * K_DIM + k0 + sc0),
            (__attribute__((address_space(3))) uint32_t*)(lhalf + wave * 512), 16, 0, 0);
        __builtin_amdgcn_global_load_lds(
            (const __attribute__((address_space(1))) uint32_t*)(gbase + (size_t)sr1 * K_DIM + k0 + sc1),
            (__attribute__((address_space(3))) uint32_t*)(lhalf + 4096 + wave * 512), 16, 0, 0);
    };

    auto FRAG = [&](const u16* lhalf, uint32_t lin) -> short8 {
        return *reinterpret_cast<const short8*>(
            reinterpret_cast<const char*>(lhalf) + swz(lin));
    };

    f32x4 acc[8][4];
#pragma unroll
    for (int m = 0; m < 8; ++m)
#pragma unroll
        for (int n = 0; n < 4; ++n) acc[m][n] = (f32x4){0.f, 0.f, 0.f, 0.f};

    short8 a[2][4], b0[2][2], b1[2][2];

    // ---- prologue: tile0 fully + tile1 B-halves; wait tile0 landed ----
    STAGE(pA[0], &lds[0][0][0][0], 0);
    STAGE(pA[1], &lds[0][0][1][0], 0);
    STAGE(pB[0], &lds[0][1][0][0], 0);
    STAGE(pB[1], &lds[0][1][1][0], 0);
    STAGE(pB[0], &lds[1][1][0][0], 64);
    STAGE(pB[1], &lds[1][1][1][0], 64);
    WAIT_VM4();
    BAR();

    // ---- main loop: iter i computes tiles a=2i (buf0), b=2i+1 (buf1) ----
    // stage schedule: P1 b.Ah0 | P2 b.Ah1 | P3 (a+2).Bh0 | P4 (a+2).Bh1 |
    //                 P5 (a+2).Ah0 | P6 (a+2).Ah1 | P7 (b+2).Bh0 | P8 (b+2).Bh1
    // vmcnt(4) at P4 (tile b landed) and P8 (tile a+2 landed).
    for (int i = 0; i < K_DIM / 128; ++i) {
        const int k_b  = (2 * i + 1) * 64;
        const int k_a2 = ((2 * i + 2) * 64) & (K_DIM - 1);
        const int k_b2 = ((2 * i + 3) * 64) & (K_DIM - 1);

        // P1: tile a, Q(mh0,nh0)
        READ_A(0, 0);
        READ_B(0, 0, b0);
        STAGE(pA[0], &lds[1][0][0][0], k_b);
        BAR(); WAIT_LGKM0();
        __builtin_amdgcn_s_setprio(1);
        QUAD(0, 0, b0);
        __builtin_amdgcn_s_setprio(0);
        BAR();

        // P2: Q(mh0,nh1)
        READ_B(0, 1, b1);
        STAGE(pA[1], &lds[1][0][1][0], k_b);
        BAR(); WAIT_LGKM0();
        __builtin_amdgcn_s_setprio(1);
        QUAD(0, 1, b1);
        __builtin_amdgcn_s_setprio(0);
        BAR();

        // P3: Q(mh1,nh0)
        READ_A(0, 1);
        STAGE(pB[0], &lds[0][1][0][0], k_a2);
        BAR(); WAIT_LGKM0();
        __builtin_amdgcn_s_setprio(1);
        QUAD(1, 0, b0);
        __builtin_amdgcn_s_setprio(0);
        BAR();

        // P4: Q(mh1,nh1) + counted vmcnt for tile b
        STAGE(pB[1], &lds[0][1][1][0], k_a2);
        BAR(); WAIT_LGKM0();
        __builtin_amdgcn_s_setprio(1);
        QUAD(1, 1, b1);
        __builtin_amdgcn_s_setprio(0);
        WAIT_VM4();
        BAR();

        // P5: tile b, Q(mh0,nh0)
        READ_A(1, 0);
        READ_B(1, 0, b0);
        STAGE(pA[0], &lds[0][0][0][0], k_a2);
        BAR(); WAIT_LGKM0();
        __builtin_amdgcn_s_setprio(1);
        QUAD(0, 0, b0);
        __builtin_amdgcn_s_setprio(0);
        BAR();

        // P6: Q(mh0,nh1)
        READ_B(1, 1, b1);
        STAGE(pA[1], &lds[0][0][1][0], k_a2);
        BAR(); WAIT_LGKM0();
        __builtin_amdgcn_s_setprio(1);
        QUAD(0, 1, b1);
        __builtin_amdgcn_s_setprio(0);
        BAR();

        // P7: Q(mh1,nh0)
        READ_A(1, 1);
        STAGE(pB[0], &lds[1][1][0][0], k_b2);
        BAR(); WAIT_LGKM0();
        __builtin_amdgcn_s_setprio(1);
        QUAD(1, 0, b0);
        __builtin_amdgcn_s_setprio(0);
        BAR();

        // P8: Q(mh1,nh1) + counted vmcnt for tile a+2
        STAGE(pB[1], &lds[1][1][1][0], k_b2);
        BAR(); WAIT_LGKM0();
        __builtin_amdgcn_s_setprio(1);
        QUAD(1, 1, b1);
        __builtin_amdgcn_s_setprio(0);
        WAIT_VM4();
        BAR();
    }

    WAIT_VM0();   // drain wrapped prefetches before ending

    // ---- epilogue: C/D layout col=lane&15, row=(lane>>4)*4+j ----
    const int orow = brow + wr * 128 + (lane >> 4) * 4;
    const int ocol = bcol + wc * 64 + (lane & 15);
#pragma unroll
    for (int n = 0; n < 4; ++n) {
        const int c = ocol + n * 16;
        const float bv = bias[c];
#pragma unroll
        for (int m = 0; m < 8; ++m) {
#pragma unroll
            for (int j = 0; j < 4; ++j) {
                C[(size_t)(orow + m * 16 + j) * N_DIM + c] = acc[m][n][j] + bv;
            }
        }
    }
}

// ---------- fallback (ws too small): correct, slow fp32 ----------
__global__ __launch_bounds__(256)
void gemm_f32_naive(const float* __restrict__ x, const float* __restrict__ w,
                    const float* __restrict__ bias, float* __restrict__ out) {
    const size_t total = (size_t)M_DIM * N_DIM;
    const size_t stride = (size_t)gridDim.x * blockDim.x;
    for (size_t idx = (size_t)blockIdx.x * blockDim.x + threadIdx.x; idx < total; idx += stride) {
        const int b = (int)(idx / N_DIM);
        const int o = (int)(idx % N_DIM);
        const float* xr = x + (size_t)b * K_DIM;
        const float* wr = w + (size_t)o * K_DIM;
        float s = bias[o];
        for (int k = 0; k < K_DIM; ++k) s = fmaf(xr[k], wr[k], s);
        out[idx] = s;
    }
}

extern "C" void kernel_launch(void* const* d_in, const int* in_sizes, int n_in,
                              void* d_out, int out_size, void* d_ws, size_t ws_size,
                              hipStream_t stream) {
    const float* x    = (const float*)d_in[0];
    const float* w    = (const float*)d_in[1];
    const float* bias = (const float*)d_in[2];
    float* out = (float*)d_out;

    const size_t xb_elems = (size_t)M_DIM * K_DIM;
    const size_t wb_elems = (size_t)N_DIM * K_DIM;
    const size_t need = (xb_elems + wb_elems) * sizeof(u16);

    if (ws_size >= need) {
        u16* xb = (u16*)d_ws;
        u16* wb = xb + xb_elems;
        cvt_f32_to_bf16_k<<<2048, 256, 0, stream>>>(x, xb, (int)(xb_elems / 8));
        cvt_f32_to_bf16_k<<<2048, 256, 0, stream>>>(w, wb, (int)(wb_elems / 8));
        const int nwg = (M_DIM / 256) * (N_DIM / 256);   // 32*16 = 512
        gemm_8phase<<<nwg, 512, 0, stream>>>(xb, wb, bias, out);
    } else {
        gemm_f32_naive<<<4096, 256, 0, stream>>>(x, w, bias, out);
    }
}

// Round 5
// 322.508 us; speedup vs baseline: 1.1458x; 1.0685x over previous
//
#include <hip/hip_runtime.h>
#include <stdint.h>

typedef unsigned short u16;
typedef __attribute__((ext_vector_type(8))) short short8;
typedef __attribute__((ext_vector_type(4))) float f32x4;

#define M_DIM 8192
#define N_DIM 4096
#define K_DIM 4096

// ---------- fp32 -> bf16 (RNE), 8 elems/thread ----------
__device__ inline u16 f32_to_bf16_rne(float f) {
    uint32_t b = __builtin_bit_cast(uint32_t, f);
    b += 0x7fffu + ((b >> 16) & 1u);
    return (u16)(b >> 16);
}

__global__ __launch_bounds__(256)
void cvt_f32_to_bf16_k(const float* __restrict__ in, u16* __restrict__ out, int n_vec8) {
    int stride = gridDim.x * blockDim.x;
    for (int i = blockIdx.x * blockDim.x + threadIdx.x; i < n_vec8; i += stride) {
        const float4* p = reinterpret_cast<const float4*>(in) + 2 * (size_t)i;
        float4 a = p[0];
        float4 b = p[1];
        float v[8] = {a.x, a.y, a.z, a.w, b.x, b.y, b.z, b.w};
        short8 r;
#pragma unroll
        for (int j = 0; j < 8; ++j) r[j] = (short)f32_to_bf16_rne(v[j]);
        *reinterpret_cast<short8*>(out + 8 * (size_t)i) = r;
    }
}

// ---------- 256x256 8-phase bf16 GEMM ----------
// A: [M][K] bf16, B: [N][K] bf16 (B^T layout), C: [M][N] f32
// 512 threads = 8 waves (2 M x 4 N); per-wave output 128x64; BK=64.
// LDS: [dbuf][mat(A/B)][half][128*64] bf16 = 128 KiB.
// Bank swizzle: rows are 128 B; S(a) = a ^ (((a>>7)&7)<<4) (involution).
//
// Read ledger (per iter): buf0 B last read P2, buf0 A last read P3,
//                          buf1 B last read P6, buf1 A last read P7.
// Stage schedule (2 halves = 4 loads/wave at each buffer-free point):
//   P3: (a+2).Bh0+Bh1 | P4: (a+2).Ah0+Ah1 | P7: (b+2).Bh0+Bh1 | P8: (b+2).Ah0+Ah1
// vmcnt(8) at P4-end drains tile b (issued prev P7/P8, 4-5 phase distance);
// vmcnt(8) at P8-end drains tile a+2 (issued P3/P4). Steady-state outstanding
// at each wait = 16 loads/wave; vmcnt(8) drains exactly the 8 oldest.

__device__ __forceinline__ uint32_t swz(uint32_t a) {
    return a ^ (((a >> 7) & 7u) << 4);
}

#define BAR() do { asm volatile("" ::: "memory"); __builtin_amdgcn_s_barrier(); asm volatile("" ::: "memory"); } while (0)
#define WAIT_LGKM0() asm volatile("s_waitcnt lgkmcnt(0)" ::: "memory")
#define WAIT_VM8() asm volatile("s_waitcnt vmcnt(8)" ::: "memory")
#define WAIT_VM0() asm volatile("s_waitcnt vmcnt(0)" ::: "memory")

// MFMA quadrant: 4 m-frags x 2 n-frags x 2 k-slices = 16 MFMA
#define QUAD(MH, NH, BB)                                                          \
    _Pragma("unroll")                                                             \
    for (int ks = 0; ks < 2; ++ks) {                                              \
        _Pragma("unroll")                                                         \
        for (int m = 0; m < 4; ++m) {                                             \
            _Pragma("unroll")                                                     \
            for (int n = 0; n < 2; ++n) {                                         \
                acc[(MH) * 4 + m][(NH) * 2 + n] =                                 \
                    __builtin_amdgcn_mfma_f32_16x16x32_bf16(                      \
                        a[ks][m], BB[ks][n], acc[(MH) * 4 + m][(NH) * 2 + n],     \
                        0, 0, 0);                                                 \
            }                                                                     \
        }                                                                         \
    }

#define READ_A(BUF, MH)                                                           \
    _Pragma("unroll")                                                             \
    for (int ks = 0; ks < 2; ++ks) {                                              \
        _Pragma("unroll")                                                         \
        for (int m = 0; m < 4; ++m) {                                             \
            a[ks][m] = FRAG(As[BUF], ((MH) * 4 + m) * 2048u + ks * 64u + aoff);   \
        }                                                                         \
    }

#define READ_B(BUF, NH, BB)                                                       \
    _Pragma("unroll")                                                             \
    for (int ks = 0; ks < 2; ++ks) {                                              \
        _Pragma("unroll")                                                         \
        for (int n = 0; n < 2; ++n) {                                             \
            BB[ks][n] = FRAG(Bs[BUF], ((NH) * 2 + n) * 2048u + ks * 64u + boff);  \
        }                                                                         \
    }

__global__ __launch_bounds__(512, 2)
void gemm_8phase(const u16* __restrict__ A, const u16* __restrict__ B,
                 const float* __restrict__ bias, float* __restrict__ C) {
    __shared__ __align__(16) u16 lds[2][2][2][128 * 64];   // 128 KiB

    const int tid  = threadIdx.x;
    const int wave = tid >> 6;
    const int lane = tid & 63;

    // T1: XCD-aware bijective swizzle (nwg=512, 512%8==0)
    const uint32_t wg = (blockIdx.x & 7u) * 64u + (blockIdx.x >> 3);
    const int bx = (int)(wg % (N_DIM / 256));
    const int by = (int)(wg / (N_DIM / 256));
    const int brow = by * 256;
    const int bcol = bx * 256;

    const int wr = wave >> 2;   // 0..1 -> 128 output rows each
    const int wc = wave & 3;    // 0..3 -> 64 output cols each

    // staging: half-tile = 128 rows x 64 cols bf16 = 1024 chunks x 16B.
    // physical chunk cp (linear global_load_lds dest) holds LOGICAL chunk
    // cl = cp ^ ((cp>>3)&7)   (16B-chunk form of S; involution)
    const uint32_t cp0 = (uint32_t)(wave * 64 + lane);
    const uint32_t cp1 = cp0 + 512u;
    const uint32_t cl0 = cp0 ^ ((cp0 >> 3) & 7u);
    const uint32_t cl1 = cp1 ^ ((cp1 >> 3) & 7u);
    const uint32_t sr0 = cl0 >> 3, sc0 = (cl0 & 7u) * 8u;   // row, col(bf16)
    const uint32_t sr1 = cl1 >> 3, sc1 = (cl1 & 7u) * 8u;

    const u16* pA[2] = { A + (size_t)(brow)       * K_DIM,
                         A + (size_t)(brow + 128) * K_DIM };
    const u16* pB[2] = { B + (size_t)(bcol)       * K_DIM,
                         B + (size_t)(bcol + 128) * K_DIM };

    // frag-read lane byte offsets within a [128][64] half (row*128B + k-part)
    const uint32_t kb   = (uint32_t)(lane >> 4) * 16u;
    const uint32_t aoff = (uint32_t)(lane & 15) * 128u + kb;
    const uint32_t boff = (uint32_t)(wc & 1) * 8192u + (uint32_t)(lane & 15) * 128u + kb;

    const u16* As[2] = { &lds[0][0][wr][0],      &lds[1][0][wr][0] };
    const u16* Bs[2] = { &lds[0][1][wc >> 1][0], &lds[1][1][wc >> 1][0] };

    auto STAGE = [&](const u16* gbase, u16* lhalf, int k0) {
        __builtin_amdgcn_global_load_lds(
            (const __attribute__((address_space(1))) uint32_t*)(gbase + (size_t)sr0 * K_DIM + k0 + sc0),
            (__attribute__((address_space(3))) uint32_t*)(lhalf + wave * 512), 16, 0, 0);
        __builtin_amdgcn_global_load_lds(
            (const __attribute__((address_space(1))) uint32_t*)(gbase + (size_t)sr1 * K_DIM + k0 + sc1),
            (__attribute__((address_space(3))) uint32_t*)(lhalf + 4096 + wave * 512), 16, 0, 0);
    };

    auto FRAG = [&](const u16* lhalf, uint32_t lin) -> short8 {
        return *reinterpret_cast<const short8*>(
            reinterpret_cast<const char*>(lhalf) + swz(lin));
    };

    f32x4 acc[8][4];
#pragma unroll
    for (int m = 0; m < 8; ++m)
#pragma unroll
        for (int n = 0; n < 4; ++n) acc[m][n] = (f32x4){0.f, 0.f, 0.f, 0.f};

    short8 a[2][4], b0[2][2], b1[2][2];

    // ---- prologue: tile a=0 (8 loads) then tile b=1 (8 loads); vmcnt(8) ----
    STAGE(pA[0], &lds[0][0][0][0], 0);    // a.Ah0
    STAGE(pA[1], &lds[0][0][1][0], 0);    // a.Ah1
    STAGE(pB[0], &lds[0][1][0][0], 0);    // a.Bh0
    STAGE(pB[1], &lds[0][1][1][0], 0);    // a.Bh1
    STAGE(pB[0], &lds[1][1][0][0], 64);   // b.Bh0
    STAGE(pB[1], &lds[1][1][1][0], 64);   // b.Bh1
    STAGE(pA[0], &lds[1][0][0][0], 64);   // b.Ah0
    STAGE(pA[1], &lds[1][0][1][0], 64);   // b.Ah1
    WAIT_VM8();                           // tile a landed; tile b (8) in flight
    BAR();

    // ---- main loop: iter i computes tiles a=2i (buf0), b=2i+1 (buf1) ----
    for (int i = 0; i < K_DIM / 128; ++i) {
        const int k_a2 = ((2 * i + 2) * 64) & (K_DIM - 1);   // wraps harmlessly last iter
        const int k_b2 = ((2 * i + 3) * 64) & (K_DIM - 1);

        // P1: tile a, Q(mh0,nh0)
        READ_A(0, 0);
        READ_B(0, 0, b0);
        BAR(); WAIT_LGKM0();
        __builtin_amdgcn_s_setprio(1);
        QUAD(0, 0, b0);
        __builtin_amdgcn_s_setprio(0);
        BAR();

        // P2: Q(mh0,nh1)  [last read of buf0 B]
        READ_B(0, 1, b1);
        BAR(); WAIT_LGKM0();
        __builtin_amdgcn_s_setprio(1);
        QUAD(0, 1, b1);
        __builtin_amdgcn_s_setprio(0);
        BAR();

        // P3: Q(mh1,nh0)  [last read of buf0 A] | stage (a+2).Bh0+Bh1
        READ_A(0, 1);
        STAGE(pB[0], &lds[0][1][0][0], k_a2);
        STAGE(pB[1], &lds[0][1][1][0], k_a2);
        BAR(); WAIT_LGKM0();
        __builtin_amdgcn_s_setprio(1);
        QUAD(1, 0, b0);
        __builtin_amdgcn_s_setprio(0);
        BAR();

        // P4: Q(mh1,nh1) | stage (a+2).Ah0+Ah1 | vmcnt(8): tile b landed
        STAGE(pA[0], &lds[0][0][0][0], k_a2);
        STAGE(pA[1], &lds[0][0][1][0], k_a2);
        BAR(); WAIT_LGKM0();
        __builtin_amdgcn_s_setprio(1);
        QUAD(1, 1, b1);
        __builtin_amdgcn_s_setprio(0);
        WAIT_VM8();
        BAR();

        // P5: tile b, Q(mh0,nh0)
        READ_A(1, 0);
        READ_B(1, 0, b0);
        BAR(); WAIT_LGKM0();
        __builtin_amdgcn_s_setprio(1);
        QUAD(0, 0, b0);
        __builtin_amdgcn_s_setprio(0);
        BAR();

        // P6: Q(mh0,nh1)  [last read of buf1 B]
        READ_B(1, 1, b1);
        BAR(); WAIT_LGKM0();
        __builtin_amdgcn_s_setprio(1);
        QUAD(0, 1, b1);
        __builtin_amdgcn_s_setprio(0);
        BAR();

        // P7: Q(mh1,nh0)  [last read of buf1 A] | stage (b+2).Bh0+Bh1
        READ_A(1, 1);
        STAGE(pB[0], &lds[1][1][0][0], k_b2);
        STAGE(pB[1], &lds[1][1][1][0], k_b2);
        BAR(); WAIT_LGKM0();
        __builtin_amdgcn_s_setprio(1);
        QUAD(1, 0, b0);
        __builtin_amdgcn_s_setprio(0);
        BAR();

        // P8: Q(mh1,nh1) | stage (b+2).Ah0+Ah1 | vmcnt(8): tile a+2 landed
        STAGE(pA[0], &lds[1][0][0][0], k_b2);
        STAGE(pA[1], &lds[1][0][1][0], k_b2);
        BAR(); WAIT_LGKM0();
        __builtin_amdgcn_s_setprio(1);
        QUAD(1, 1, b1);
        __builtin_amdgcn_s_setprio(0);
        WAIT_VM8();
        BAR();
    }

    WAIT_VM0();   // drain wrapped prefetches before epilogue

    // ---- epilogue: C/D layout col=lane&15, row=(lane>>4)*4+j ----
    const int orow = brow + wr * 128 + (lane >> 4) * 4;
    const int ocol = bcol + wc * 64 + (lane & 15);
#pragma unroll
    for (int n = 0; n < 4; ++n) {
        const int c = ocol + n * 16;
        const float bv = bias[c];
#pragma unroll
        for (int m = 0; m < 8; ++m) {
#pragma unroll
            for (int j = 0; j < 4; ++j) {
                C[(size_t)(orow + m * 16 + j) * N_DIM + c] = acc[m][n][j] + bv;
            }
        }
    }
}

// ---------- fallback (ws too small): correct, slow fp32 ----------
__global__ __launch_bounds__(256)
void gemm_f32_naive(const float* __restrict__ x, const float* __restrict__ w,
                    const float* __restrict__ bias, float* __restrict__ out) {
    const size_t total = (size_t)M_DIM * N_DIM;
    const size_t stride = (size_t)gridDim.x * blockDim.x;
    for (size_t idx = (size_t)blockIdx.x * blockDim.x + threadIdx.x; idx < total; idx += stride) {
        const int b = (int)(idx / N_DIM);
        const int o = (int)(idx % N_DIM);
        const float* xr = x + (size_t)b * K_DIM;
        const float* wr = w + (size_t)o * K_DIM;
        float s = bias[o];
        for (int k = 0; k < K_DIM; ++k) s = fmaf(xr[k], wr[k], s);
        out[idx] = s;
    }
}

extern "C" void kernel_launch(void* const* d_in, const int* in_sizes, int n_in,
                              void* d_out, int out_size, void* d_ws, size_t ws_size,
                              hipStream_t stream) {
    const float* x    = (const float*)d_in[0];
    const float* w    = (const float*)d_in[1];
    const float* bias = (const float*)d_in[2];
    float* out = (float*)d_out;

    const size_t xb_elems = (size_t)M_DIM * K_DIM;
    const size_t wb_elems = (size_t)N_DIM * K_DIM;
    const size_t need = (xb_elems + wb_elems) * sizeof(u16);

    if (ws_size >= need) {
        u16* xb = (u16*)d_ws;
        u16* wb = xb + xb_elems;
        cvt_f32_to_bf16_k<<<2048, 256, 0, stream>>>(x, xb, (int)(xb_elems / 8));
        cvt_f32_to_bf16_k<<<2048, 256, 0, stream>>>(w, wb, (int)(wb_elems / 8));
        const int nwg = (M_DIM / 256) * (N_DIM / 256);   // 32*16 = 512
        gemm_8phase<<<nwg, 512, 0, stream>>>(xb, wb, bias, out);
    } else {
        gemm_f32_naive<<<4096, 256, 0, stream>>>(x, w, bias, out);
    }
}

// Round 6
// 285.469 us; speedup vs baseline: 1.2944x; 1.1298x over previous
//
#include <hip/hip_runtime.h>
#include <stdint.h>

typedef unsigned short u16;
typedef __attribute__((ext_vector_type(8))) short short8;
typedef __attribute__((ext_vector_type(4))) float f32x4;

#define M_DIM 8192
#define N_DIM 4096
#define K_DIM 4096

// ---------- fp32 -> bf16 (RNE), 8 elems/thread ----------
__device__ inline u16 f32_to_bf16_rne(float f) {
    uint32_t b = __builtin_bit_cast(uint32_t, f);
    b += 0x7fffu + ((b >> 16) & 1u);
    return (u16)(b >> 16);
}

__global__ __launch_bounds__(256)
void cvt_f32_to_bf16_k(const float* __restrict__ in, u16* __restrict__ out, int n_vec8) {
    int stride = gridDim.x * blockDim.x;
    for (int i = blockIdx.x * blockDim.x + threadIdx.x; i < n_vec8; i += stride) {
        const float4* p = reinterpret_cast<const float4*>(in) + 2 * (size_t)i;
        float4 a = p[0];
        float4 b = p[1];
        float v[8] = {a.x, a.y, a.z, a.w, b.x, b.y, b.z, b.w};
        short8 r;
#pragma unroll
        for (int j = 0; j < 8; ++j) r[j] = (short)f32_to_bf16_rne(v[j]);
        *reinterpret_cast<short8*>(out + 8 * (size_t)i) = r;
    }
}

// ---------- 256x256 8-phase bf16 GEMM ----------
// A: [M][K] bf16, B: [N][K] bf16 (B^T layout), C: [M][N] f32
// 512 threads = 8 waves (2 M x 4 N); per-wave output 128x64; BK=64.
// LDS: [dbuf][mat(A/B)][half][128*64] bf16 = 128 KiB.
// Bank swizzle S(a) = a ^ (((a>>7)&7)<<4). For every fragment read the key
// (row&7) == (lane&7), so S folds into PRECOMPUTED per-lane base pointers:
//   base[ks] = lds_half + ((ks*64 + off) ^ ((lane&7)<<4))
// and each ds_read is base[ks] + compile-time offset (frag*2048 [+ MH*8192]).
//
// Stage schedule (unchanged from r5): P3 (a+2).B, P4 (a+2).A, P7 (b+2).B,
// P8 (b+2).A; vmcnt(8) at P4/P8. Read hoisting: P2's B-NH1 reads issue in P1's
// MFMA slot, P3's A-MH1 in P2, P6's B-NH1 in P5, P7's A-MH1 in P6 (buffers
// already barrier-published there). P1/P5 reads cannot hoist (their buffer is
// only valid after the preceding VM8+BAR).

#define BAR() do { asm volatile("" ::: "memory"); __builtin_amdgcn_s_barrier(); asm volatile("" ::: "memory"); } while (0)
#define WAIT_LGKM0() asm volatile("s_waitcnt lgkmcnt(0)" ::: "memory")
#define WAIT_VM8() asm volatile("s_waitcnt vmcnt(8)" ::: "memory")
#define WAIT_VM0() asm volatile("s_waitcnt vmcnt(0)" ::: "memory")
#define SB0() __builtin_amdgcn_sched_barrier(0)

// 16 MFMA: 4 m-frags x 2 n-frags x 2 k-slices
#define QUAD(AA, BB, MH, NH)                                                      \
    _Pragma("unroll")                                                             \
    for (int ks = 0; ks < 2; ++ks) {                                              \
        _Pragma("unroll")                                                         \
        for (int m = 0; m < 4; ++m) {                                             \
            _Pragma("unroll")                                                     \
            for (int n = 0; n < 2; ++n) {                                         \
                acc[(MH) * 4 + m][(NH) * 2 + n] =                                 \
                    __builtin_amdgcn_mfma_f32_16x16x32_bf16(                      \
                        AA[ks][m], BB[ks][n], acc[(MH) * 4 + m][(NH) * 2 + n],    \
                        0, 0, 0);                                                 \
            }                                                                     \
        }                                                                         \
    }

// A fragment reads: base pointers P0(ks=0)/P1(ks=1), MHOFF in {0, 8192} bytes
#define READ_A(P0, P1, AA, MHOFF)                                                 \
    _Pragma("unroll")                                                             \
    for (int m = 0; m < 4; ++m) {                                                 \
        AA[0][m] = *reinterpret_cast<const short8*>((P0) + (MHOFF) + m * 2048);   \
        AA[1][m] = *reinterpret_cast<const short8*>((P1) + (MHOFF) + m * 2048);   \
    }

// B fragment reads: NHOFF in {0, 4096} bytes
#define READ_B(P0, P1, BB, NHOFF)                                                 \
    _Pragma("unroll")                                                             \
    for (int n = 0; n < 2; ++n) {                                                 \
        BB[0][n] = *reinterpret_cast<const short8*>((P0) + (NHOFF) + n * 2048);   \
        BB[1][n] = *reinterpret_cast<const short8*>((P1) + (NHOFF) + n * 2048);   \
    }

__global__ __launch_bounds__(512, 2)
void gemm_8phase(const u16* __restrict__ A, const u16* __restrict__ B,
                 const float* __restrict__ bias, float* __restrict__ C) {
    __shared__ __align__(16) u16 lds[2][2][2][128 * 64];   // 128 KiB

    const int tid  = threadIdx.x;
    const int wave = tid >> 6;
    const int lane = tid & 63;

    // T1: XCD-aware bijective swizzle (nwg=512, 512%8==0)
    const uint32_t wg = (blockIdx.x & 7u) * 64u + (blockIdx.x >> 3);
    const int bx = (int)(wg % (N_DIM / 256));
    const int by = (int)(wg / (N_DIM / 256));
    const int brow = by * 256;
    const int bcol = bx * 256;

    const int wr = wave >> 2;   // 0..1 -> 128 output rows each
    const int wc = wave & 3;    // 0..3 -> 64 output cols each

    // staging: half-tile = 128x64 bf16 = 1024 chunks x 16B. Physical chunk cp
    // (linear global_load_lds dest) holds LOGICAL chunk cl = cp ^ ((cp>>3)&7).
    const uint32_t cp0 = (uint32_t)(wave * 64 + lane);
    const uint32_t cp1 = cp0 + 512u;
    const uint32_t cl0 = cp0 ^ ((cp0 >> 3) & 7u);
    const uint32_t cl1 = cp1 ^ ((cp1 >> 3) & 7u);
    const uint32_t sr0 = cl0 >> 3, sc0 = (cl0 & 7u) * 8u;
    const uint32_t sr1 = cl1 >> 3, sc1 = (cl1 & 7u) * 8u;

    const u16* pA[2] = { A + (size_t)(brow)       * K_DIM,
                         A + (size_t)(brow + 128) * K_DIM };
    const u16* pB[2] = { B + (size_t)(bcol)       * K_DIM,
                         B + (size_t)(bcol + 128) * K_DIM };

    // precomputed swizzled per-lane ds_read bases
    const uint32_t kb   = (uint32_t)(lane >> 4) * 16u;
    const uint32_t sw   = (uint32_t)(lane & 7) << 4;
    const uint32_t aoff = (uint32_t)(lane & 15) * 128u + kb;
    const uint32_t boff = (uint32_t)(wc & 1) * 8192u + (uint32_t)(lane & 15) * 128u + kb;

    const char* As0 = (const char*)&lds[0][0][wr][0];
    const char* As1 = (const char*)&lds[1][0][wr][0];
    const char* Bs0 = (const char*)&lds[0][1][wc >> 1][0];
    const char* Bs1 = (const char*)&lds[1][1][wc >> 1][0];

    const char* pA0k0 = As0 + ((aoff)        ^ sw);
    const char* pA0k1 = As0 + ((aoff + 64u)  ^ sw);
    const char* pA1k0 = As1 + ((aoff)        ^ sw);
    const char* pA1k1 = As1 + ((aoff + 64u)  ^ sw);
    const char* pB0k0 = Bs0 + ((boff)        ^ sw);
    const char* pB0k1 = Bs0 + ((boff + 64u)  ^ sw);
    const char* pB1k0 = Bs1 + ((boff)        ^ sw);
    const char* pB1k1 = Bs1 + ((boff + 64u)  ^ sw);

    auto STAGE = [&](const u16* gbase, u16* lhalf, int k0) {
        __builtin_amdgcn_global_load_lds(
            (const __attribute__((address_space(1))) uint32_t*)(gbase + (size_t)sr0 * K_DIM + k0 + sc0),
            (__attribute__((address_space(3))) uint32_t*)(lhalf + wave * 512), 16, 0, 0);
        __builtin_amdgcn_global_load_lds(
            (const __attribute__((address_space(1))) uint32_t*)(gbase + (size_t)sr1 * K_DIM + k0 + sc1),
            (__attribute__((address_space(3))) uint32_t*)(lhalf + 4096 + wave * 512), 16, 0, 0);
    };

    f32x4 acc[8][4];
#pragma unroll
    for (int m = 0; m < 8; ++m)
#pragma unroll
        for (int n = 0; n < 4; ++n) acc[m][n] = (f32x4){0.f, 0.f, 0.f, 0.f};

    short8 a0[2][4], a1[2][4], b0[2][2], b1[2][2];

    // ---- prologue: tile a=0 then tile b=1; vmcnt(8) ----
    STAGE(pA[0], &lds[0][0][0][0], 0);
    STAGE(pA[1], &lds[0][0][1][0], 0);
    STAGE(pB[0], &lds[0][1][0][0], 0);
    STAGE(pB[1], &lds[0][1][1][0], 0);
    STAGE(pB[0], &lds[1][1][0][0], 64);
    STAGE(pB[1], &lds[1][1][1][0], 64);
    STAGE(pA[0], &lds[1][0][0][0], 64);
    STAGE(pA[1], &lds[1][0][1][0], 64);
    WAIT_VM8();
    BAR();

    // ---- main loop: iter i computes tiles a=2i (buf0), b=2i+1 (buf1) ----
    for (int i = 0; i < K_DIM / 128; ++i) {
        const int k_a2 = ((2 * i + 2) * 64) & (K_DIM - 1);   // wraps harmlessly last iter
        const int k_b2 = ((2 * i + 3) * 64) & (K_DIM - 1);

        // P1: Q(0,0) | pre-reads a0,b0 | hoist b1 (buf0-B valid)
        READ_A(pA0k0, pA0k1, a0, 0);
        READ_B(pB0k0, pB0k1, b0, 0);
        BAR(); WAIT_LGKM0();
        READ_B(pB0k0, pB0k1, b1, 4096);
        SB0();
        __builtin_amdgcn_s_setprio(1);
        QUAD(a0, b0, 0, 0);
        __builtin_amdgcn_s_setprio(0);
        BAR();

        // P2: Q(0,1) | hoist a1 (buf0-A valid)
        BAR(); WAIT_LGKM0();
        READ_A(pA0k0, pA0k1, a1, 8192);
        SB0();
        __builtin_amdgcn_s_setprio(1);
        QUAD(a0, b1, 0, 1);
        __builtin_amdgcn_s_setprio(0);
        BAR();

        // P3: Q(1,0) | stage (a+2).Bh0+Bh1
        STAGE(pB[0], &lds[0][1][0][0], k_a2);
        STAGE(pB[1], &lds[0][1][1][0], k_a2);
        BAR(); WAIT_LGKM0();
        __builtin_amdgcn_s_setprio(1);
        QUAD(a1, b0, 1, 0);
        __builtin_amdgcn_s_setprio(0);
        BAR();

        // P4: Q(1,1) | stage (a+2).Ah0+Ah1 | vmcnt(8): tile b landed
        STAGE(pA[0], &lds[0][0][0][0], k_a2);
        STAGE(pA[1], &lds[0][0][1][0], k_a2);
        BAR(); WAIT_LGKM0();
        __builtin_amdgcn_s_setprio(1);
        QUAD(a1, b1, 1, 1);
        __builtin_amdgcn_s_setprio(0);
        WAIT_VM8();
        BAR();

        // P5: tile b, Q(0,0) | pre-reads a0,b0 | hoist b1
        READ_A(pA1k0, pA1k1, a0, 0);
        READ_B(pB1k0, pB1k1, b0, 0);
        BAR(); WAIT_LGKM0();
        READ_B(pB1k0, pB1k1, b1, 4096);
        SB0();
        __builtin_amdgcn_s_setprio(1);
        QUAD(a0, b0, 0, 0);
        __builtin_amdgcn_s_setprio(0);
        BAR();

        // P6: Q(0,1) | hoist a1
        BAR(); WAIT_LGKM0();
        READ_A(pA1k0, pA1k1, a1, 8192);
        SB0();
        __builtin_amdgcn_s_setprio(1);
        QUAD(a0, b1, 0, 1);
        __builtin_amdgcn_s_setprio(0);
        BAR();

        // P7: Q(1,0) | stage (b+2).Bh0+Bh1
        STAGE(pB[0], &lds[1][1][0][0], k_b2);
        STAGE(pB[1], &lds[1][1][1][0], k_b2);
        BAR(); WAIT_LGKM0();
        __builtin_amdgcn_s_setprio(1);
        QUAD(a1, b0, 1, 0);
        __builtin_amdgcn_s_setprio(0);
        BAR();

        // P8: Q(1,1) | stage (b+2).Ah0+Ah1 | vmcnt(8): tile a+2 landed
        STAGE(pA[0], &lds[1][0][0][0], k_b2);
        STAGE(pA[1], &lds[1][0][1][0], k_b2);
        BAR(); WAIT_LGKM0();
        __builtin_amdgcn_s_setprio(1);
        QUAD(a1, b1, 1, 1);
        __builtin_amdgcn_s_setprio(0);
        WAIT_VM8();
        BAR();
    }

    WAIT_VM0();   // drain wrapped prefetches before epilogue

    // ---- epilogue: C/D layout col=lane&15, row=(lane>>4)*4+j ----
    const int orow = brow + wr * 128 + (lane >> 4) * 4;
    const int ocol = bcol + wc * 64 + (lane & 15);
#pragma unroll
    for (int n = 0; n < 4; ++n) {
        const int c = ocol + n * 16;
        const float bv = bias[c];
#pragma unroll
        for (int m = 0; m < 8; ++m) {
#pragma unroll
            for (int j = 0; j < 4; ++j) {
                C[(size_t)(orow + m * 16 + j) * N_DIM + c] = acc[m][n][j] + bv;
            }
        }
    }
}

// ---------- fallback (ws too small): correct, slow fp32 ----------
__global__ __launch_bounds__(256)
void gemm_f32_naive(const float* __restrict__ x, const float* __restrict__ w,
                    const float* __restrict__ bias, float* __restrict__ out) {
    const size_t total = (size_t)M_DIM * N_DIM;
    const size_t stride = (size_t)gridDim.x * blockDim.x;
    for (size_t idx = (size_t)blockIdx.x * blockDim.x + threadIdx.x; idx < total; idx += stride) {
        const int b = (int)(idx / N_DIM);
        const int o = (int)(idx % N_DIM);
        const float* xr = x + (size_t)b * K_DIM;
        const float* wr = w + (size_t)o * K_DIM;
        float s = bias[o];
        for (int k = 0; k < K_DIM; ++k) s = fmaf(xr[k], wr[k], s);
        out[idx] = s;
    }
}

extern "C" void kernel_launch(void* const* d_in, const int* in_sizes, int n_in,
                              void* d_out, int out_size, void* d_ws, size_t ws_size,
                              hipStream_t stream) {
    const float* x    = (const float*)d_in[0];
    const float* w    = (const float*)d_in[1];
    const float* bias = (const float*)d_in[2];
    float* out = (float*)d_out;

    const size_t xb_elems = (size_t)M_DIM * K_DIM;
    const size_t wb_elems = (size_t)N_DIM * K_DIM;
    const size_t need = (xb_elems + wb_elems) * sizeof(u16);

    if (ws_size >= need) {
        u16* xb = (u16*)d_ws;
        u16* wb = xb + xb_elems;
        cvt_f32_to_bf16_k<<<2048, 256, 0, stream>>>(x, xb, (int)(xb_elems / 8));
        cvt_f32_to_bf16_k<<<2048, 256, 0, stream>>>(w, wb, (int)(wb_elems / 8));
        const int nwg = (M_DIM / 256) * (N_DIM / 256);   // 32*16 = 512
        gemm_8phase<<<nwg, 512, 0, stream>>>(xb, wb, bias, out);
    } else {
        gemm_f32_naive<<<4096, 256, 0, stream>>>(x, w, bias, out);
    }
}

// Round 7
// 275.319 us; speedup vs baseline: 1.3422x; 1.0369x over previous
//
#include <hip/hip_runtime.h>
#include <stdint.h>

typedef unsigned short u16;
typedef __attribute__((ext_vector_type(8))) short short8;
typedef __attribute__((ext_vector_type(4))) float f32x4;

#define M_DIM 8192
#define N_DIM 4096
#define K_DIM 4096

// ---------- fp32 -> bf16 (RNE), 8 elems/thread ----------
__device__ inline u16 f32_to_bf16_rne(float f) {
    uint32_t b = __builtin_bit_cast(uint32_t, f);
    b += 0x7fffu + ((b >> 16) & 1u);
    return (u16)(b >> 16);
}

__global__ __launch_bounds__(256)
void cvt_f32_to_bf16_k(const float* __restrict__ in, u16* __restrict__ out, int n_vec8) {
    int stride = gridDim.x * blockDim.x;
    for (int i = blockIdx.x * blockDim.x + threadIdx.x; i < n_vec8; i += stride) {
        const float4* p = reinterpret_cast<const float4*>(in) + 2 * (size_t)i;
        float4 a = p[0];
        float4 b = p[1];
        float v[8] = {a.x, a.y, a.z, a.w, b.x, b.y, b.z, b.w};
        short8 r;
#pragma unroll
        for (int j = 0; j < 8; ++j) r[j] = (short)f32_to_bf16_rne(v[j]);
        *reinterpret_cast<short8*>(out + 8 * (size_t)i) = r;
    }
}

// ---------- 256x256 8-phase bf16 GEMM ----------
// A: [M][K] bf16, B: [N][K] bf16 (B^T layout), C: [M][N] f32
// 512 threads = 8 waves (2 M x 4 N); per-wave output 128x64; BK=64.
// LDS: [dbuf][mat(A/B)][half][128*64] bf16 = 128 KiB.
// Bank swizzle S(a) = a ^ (((a>>7)&7)<<4), folded into precomputed per-lane
// base pointers (key == (lane&7) for every fragment read).
//
// Schedule (all reads hoisted into MFMA slots; vmcnt one phase early):
//   P1: [lgkm0][read b1]     MFMA Q00(a0,b0)
//   P2: [lgkm0][read a1]     MFMA Q01(a0,b1)
//   P3: STAGE (a+2).B | Q10(a1,b0) | vmcnt(4)  -> tile b published at close
//   P4: STAGE (a+2).A | [read next a0,b0 from buf1] Q11(a1,b1)
//   P5..P8 mirror for tile b / (b+2), vmcnt(4) at P7.
// Per-wave loads: 4 at P3,P4,P7,P8. vmcnt(4)@P3 drains tile b (issued prev
// P7/P8, 3-4 phases earlier); vmcnt(4)@P7 drains tile a+2 (issued P3/P4).
// sched_barrier(0) after every lgkm0 (rule #18: stop MFMA hoisting past it).

#define BAR() do { asm volatile("" ::: "memory"); __builtin_amdgcn_s_barrier(); asm volatile("" ::: "memory"); } while (0)
#define WAIT_LGKM0() do { asm volatile("s_waitcnt lgkmcnt(0)" ::: "memory"); __builtin_amdgcn_sched_barrier(0); } while (0)
#define WAIT_VM8() asm volatile("s_waitcnt vmcnt(8)" ::: "memory")
#define WAIT_VM4() asm volatile("s_waitcnt vmcnt(4)" ::: "memory")
#define WAIT_VM0() asm volatile("s_waitcnt vmcnt(0)" ::: "memory")
#define SB0() __builtin_amdgcn_sched_barrier(0)

// 16 MFMA: 4 m-frags x 2 n-frags x 2 k-slices
#define QUAD(AA, BB, MH, NH)                                                      \
    _Pragma("unroll")                                                             \
    for (int ks = 0; ks < 2; ++ks) {                                              \
        _Pragma("unroll")                                                         \
        for (int m = 0; m < 4; ++m) {                                             \
            _Pragma("unroll")                                                     \
            for (int n = 0; n < 2; ++n) {                                         \
                acc[(MH) * 4 + m][(NH) * 2 + n] =                                 \
                    __builtin_amdgcn_mfma_f32_16x16x32_bf16(                      \
                        AA[ks][m], BB[ks][n], acc[(MH) * 4 + m][(NH) * 2 + n],    \
                        0, 0, 0);                                                 \
            }                                                                     \
        }                                                                         \
    }

// A fragment reads: base pointers P0(ks=0)/P1(ks=1), MHOFF in {0, 8192} bytes
#define READ_A(P0, P1, AA, MHOFF)                                                 \
    _Pragma("unroll")                                                             \
    for (int m = 0; m < 4; ++m) {                                                 \
        AA[0][m] = *reinterpret_cast<const short8*>((P0) + (MHOFF) + m * 2048);   \
        AA[1][m] = *reinterpret_cast<const short8*>((P1) + (MHOFF) + m * 2048);   \
    }

// B fragment reads: NHOFF in {0, 4096} bytes
#define READ_B(P0, P1, BB, NHOFF)                                                 \
    _Pragma("unroll")                                                             \
    for (int n = 0; n < 2; ++n) {                                                 \
        BB[0][n] = *reinterpret_cast<const short8*>((P0) + (NHOFF) + n * 2048);   \
        BB[1][n] = *reinterpret_cast<const short8*>((P1) + (NHOFF) + n * 2048);   \
    }

__global__ __launch_bounds__(512, 2)
void gemm_8phase(const u16* __restrict__ A, const u16* __restrict__ B,
                 const float* __restrict__ bias, float* __restrict__ C) {
    __shared__ __align__(16) u16 lds[2][2][2][128 * 64];   // 128 KiB

    const int tid  = threadIdx.x;
    const int wave = tid >> 6;
    const int lane = tid & 63;

    // T1: XCD-aware bijective swizzle (nwg=512, 512%8==0)
    const uint32_t wg = (blockIdx.x & 7u) * 64u + (blockIdx.x >> 3);
    const int bx = (int)(wg % (N_DIM / 256));
    const int by = (int)(wg / (N_DIM / 256));
    const int brow = by * 256;
    const int bcol = bx * 256;

    const int wr = wave >> 2;   // 0..1 -> 128 output rows each
    const int wc = wave & 3;    // 0..3 -> 64 output cols each

    // staging: half-tile = 128x64 bf16 = 1024 chunks x 16B. Physical chunk cp
    // (linear global_load_lds dest) holds LOGICAL chunk cl = cp ^ ((cp>>3)&7).
    const uint32_t cp0 = (uint32_t)(wave * 64 + lane);
    const uint32_t cp1 = cp0 + 512u;
    const uint32_t cl0 = cp0 ^ ((cp0 >> 3) & 7u);
    const uint32_t cl1 = cp1 ^ ((cp1 >> 3) & 7u);
    const uint32_t sr0 = cl0 >> 3, sc0 = (cl0 & 7u) * 8u;
    const uint32_t sr1 = cl1 >> 3, sc1 = (cl1 & 7u) * 8u;

    const u16* pA[2] = { A + (size_t)(brow)       * K_DIM,
                         A + (size_t)(brow + 128) * K_DIM };
    const u16* pB[2] = { B + (size_t)(bcol)       * K_DIM,
                         B + (size_t)(bcol + 128) * K_DIM };

    // precomputed swizzled per-lane ds_read bases
    const uint32_t kb   = (uint32_t)(lane >> 4) * 16u;
    const uint32_t sw   = (uint32_t)(lane & 7) << 4;
    const uint32_t aoff = (uint32_t)(lane & 15) * 128u + kb;
    const uint32_t boff = (uint32_t)(wc & 1) * 8192u + (uint32_t)(lane & 15) * 128u + kb;

    const char* As0 = (const char*)&lds[0][0][wr][0];
    const char* As1 = (const char*)&lds[1][0][wr][0];
    const char* Bs0 = (const char*)&lds[0][1][wc >> 1][0];
    const char* Bs1 = (const char*)&lds[1][1][wc >> 1][0];

    const char* pA0k0 = As0 + ((aoff)        ^ sw);
    const char* pA0k1 = As0 + ((aoff + 64u)  ^ sw);
    const char* pA1k0 = As1 + ((aoff)        ^ sw);
    const char* pA1k1 = As1 + ((aoff + 64u)  ^ sw);
    const char* pB0k0 = Bs0 + ((boff)        ^ sw);
    const char* pB0k1 = Bs0 + ((boff + 64u)  ^ sw);
    const char* pB1k0 = Bs1 + ((boff)        ^ sw);
    const char* pB1k1 = Bs1 + ((boff + 64u)  ^ sw);

    auto STAGE = [&](const u16* gbase, u16* lhalf, int k0) {
        __builtin_amdgcn_global_load_lds(
            (const __attribute__((address_space(1))) uint32_t*)(gbase + (size_t)sr0 * K_DIM + k0 + sc0),
            (__attribute__((address_space(3))) uint32_t*)(lhalf + wave * 512), 16, 0, 0);
        __builtin_amdgcn_global_load_lds(
            (const __attribute__((address_space(1))) uint32_t*)(gbase + (size_t)sr1 * K_DIM + k0 + sc1),
            (__attribute__((address_space(3))) uint32_t*)(lhalf + 4096 + wave * 512), 16, 0, 0);
    };

    f32x4 acc[8][4];
#pragma unroll
    for (int m = 0; m < 8; ++m)
#pragma unroll
        for (int n = 0; n < 4; ++n) acc[m][n] = (f32x4){0.f, 0.f, 0.f, 0.f};

    short8 a0[2][4], a1[2][4], b0[2][2], b1[2][2];

    // ---- prologue: tile a=0 then tile b=1; vmcnt(8); pre-read a0,b0 ----
    STAGE(pA[0], &lds[0][0][0][0], 0);
    STAGE(pA[1], &lds[0][0][1][0], 0);
    STAGE(pB[0], &lds[0][1][0][0], 0);
    STAGE(pB[1], &lds[0][1][1][0], 0);
    STAGE(pB[0], &lds[1][1][0][0], 64);
    STAGE(pB[1], &lds[1][1][1][0], 64);
    STAGE(pA[0], &lds[1][0][0][0], 64);
    STAGE(pA[1], &lds[1][0][1][0], 64);
    WAIT_VM8();
    BAR();
    READ_A(pA0k0, pA0k1, a0, 0);
    READ_B(pB0k0, pB0k1, b0, 0);

    // ---- main loop: iter i computes tiles a=2i (buf0), b=2i+1 (buf1) ----
    for (int i = 0; i < K_DIM / 128; ++i) {
        const int k_a2 = ((2 * i + 2) * 64) & (K_DIM - 1);   // wraps harmlessly last iter
        const int k_b2 = ((2 * i + 3) * 64) & (K_DIM - 1);

        // P1: Q(0,0) | slot-read b1
        BAR(); WAIT_LGKM0();
        READ_B(pB0k0, pB0k1, b1, 4096);
        SB0();
        __builtin_amdgcn_s_setprio(1);
        QUAD(a0, b0, 0, 0);
        __builtin_amdgcn_s_setprio(0);
        BAR();

        // P2: Q(0,1) | slot-read a1
        BAR(); WAIT_LGKM0();
        READ_A(pA0k0, pA0k1, a1, 8192);
        SB0();
        __builtin_amdgcn_s_setprio(1);
        QUAD(a0, b1, 0, 1);
        __builtin_amdgcn_s_setprio(0);
        BAR();

        // P3: Q(1,0) | stage (a+2).B | vmcnt(4): tile b landed -> published at close
        STAGE(pB[0], &lds[0][1][0][0], k_a2);
        STAGE(pB[1], &lds[0][1][1][0], k_a2);
        BAR(); WAIT_LGKM0();
        __builtin_amdgcn_s_setprio(1);
        QUAD(a1, b0, 1, 0);
        __builtin_amdgcn_s_setprio(0);
        WAIT_VM4();
        BAR();

        // P4: Q(1,1) | stage (a+2).A | slot-read next a0,b0 from buf1 (tile b)
        STAGE(pA[0], &lds[0][0][0][0], k_a2);
        STAGE(pA[1], &lds[0][0][1][0], k_a2);
        BAR(); WAIT_LGKM0();
        READ_A(pA1k0, pA1k1, a0, 0);
        READ_B(pB1k0, pB1k1, b0, 0);
        SB0();
        __builtin_amdgcn_s_setprio(1);
        QUAD(a1, b1, 1, 1);
        __builtin_amdgcn_s_setprio(0);
        BAR();

        // P5: tile b, Q(0,0) | slot-read b1
        BAR(); WAIT_LGKM0();
        READ_B(pB1k0, pB1k1, b1, 4096);
        SB0();
        __builtin_amdgcn_s_setprio(1);
        QUAD(a0, b0, 0, 0);
        __builtin_amdgcn_s_setprio(0);
        BAR();

        // P6: Q(0,1) | slot-read a1
        BAR(); WAIT_LGKM0();
        READ_A(pA1k0, pA1k1, a1, 8192);
        SB0();
        __builtin_amdgcn_s_setprio(1);
        QUAD(a0, b1, 0, 1);
        __builtin_amdgcn_s_setprio(0);
        BAR();

        // P7: Q(1,0) | stage (b+2).B | vmcnt(4): tile a+2 landed -> published at close
        STAGE(pB[0], &lds[1][1][0][0], k_b2);
        STAGE(pB[1], &lds[1][1][1][0], k_b2);
        BAR(); WAIT_LGKM0();
        __builtin_amdgcn_s_setprio(1);
        QUAD(a1, b0, 1, 0);
        __builtin_amdgcn_s_setprio(0);
        WAIT_VM4();
        BAR();

        // P8: Q(1,1) | stage (b+2).A | slot-read next a0,b0 from buf0 (tile a+2)
        STAGE(pA[0], &lds[1][0][0][0], k_b2);
        STAGE(pA[1], &lds[1][0][1][0], k_b2);
        BAR(); WAIT_LGKM0();
        READ_A(pA0k0, pA0k1, a0, 0);
        READ_B(pB0k0, pB0k1, b0, 0);
        SB0();
        __builtin_amdgcn_s_setprio(1);
        QUAD(a1, b1, 1, 1);
        __builtin_amdgcn_s_setprio(0);
        BAR();
    }

    WAIT_VM0();   // drain wrapped prefetches before epilogue

    // ---- epilogue: C/D layout col=lane&15, row=(lane>>4)*4+j ----
    const int orow = brow + wr * 128 + (lane >> 4) * 4;
    const int ocol = bcol + wc * 64 + (lane & 15);
#pragma unroll
    for (int n = 0; n < 4; ++n) {
        const int c = ocol + n * 16;
        const float bv = bias[c];
#pragma unroll
        for (int m = 0; m < 8; ++m) {
#pragma unroll
            for (int j = 0; j < 4; ++j) {
                C[(size_t)(orow + m * 16 + j) * N_DIM + c] = acc[m][n][j] + bv;
            }
        }
    }
}

// ---------- fallback (ws too small): correct, slow fp32 ----------
__global__ __launch_bounds__(256)
void gemm_f32_naive(const float* __restrict__ x, const float* __restrict__ w,
                    const float* __restrict__ bias, float* __restrict__ out) {
    const size_t total = (size_t)M_DIM * N_DIM;
    const size_t stride = (size_t)gridDim.x * blockDim.x;
    for (size_t idx = (size_t)blockIdx.x * blockDim.x + threadIdx.x; idx < total; idx += stride) {
        const int b = (int)(idx / N_DIM);
        const int o = (int)(idx % N_DIM);
        const float* xr = x + (size_t)b * K_DIM;
        const float* wr = w + (size_t)o * K_DIM;
        float s = bias[o];
        for (int k = 0; k < K_DIM; ++k) s = fmaf(xr[k], wr[k], s);
        out[idx] = s;
    }
}

extern "C" void kernel_launch(void* const* d_in, const int* in_sizes, int n_in,
                              void* d_out, int out_size, void* d_ws, size_t ws_size,
                              hipStream_t stream) {
    const float* x    = (const float*)d_in[0];
    const float* w    = (const float*)d_in[1];
    const float* bias = (const float*)d_in[2];
    float* out = (float*)d_out;

    const size_t xb_elems = (size_t)M_DIM * K_DIM;
    const size_t wb_elems = (size_t)N_DIM * K_DIM;
    const size_t need = (xb_elems + wb_elems) * sizeof(u16);

    if (ws_size >= need) {
        u16* xb = (u16*)d_ws;
        u16* wb = xb + xb_elems;
        cvt_f32_to_bf16_k<<<2048, 256, 0, stream>>>(x, xb, (int)(xb_elems / 8));
        cvt_f32_to_bf16_k<<<2048, 256, 0, stream>>>(w, wb, (int)(wb_elems / 8));
        const int nwg = (M_DIM / 256) * (N_DIM / 256);   // 32*16 = 512
        gemm_8phase<<<nwg, 512, 0, stream>>>(xb, wb, bias, out);
    } else {
        gemm_f32_naive<<<4096, 256, 0, stream>>>(x, w, bias, out);
    }
}